// Round 1
// baseline (862.948 us; speedup 1.0000x reference)
//
#include <hip/hip_runtime.h>
#include <math.h>

// LogSimpleSlater: A[b][i][j] = cos/sin(k_j . r_{b,i}); out[b] = log|det A_b|.
// One workgroup (256 threads) per walker. Matrix in LDS (128 x 132 fp32).
// Blocked LU, NB=16: register-resident panel on wave 0 (implicit row
// permutation via slot tracking), column-parallel swaps + U12 forward-sub,
// 8x4-register-tile trailing GEMM. log|det| = sum log|pivot|.

#define NN 128
#define LDA 132      // row pitch in floats: 132 = 33*4 -> conflict-free b128 column access
#define NB 16
#define NTHREADS 256

__device__ __forceinline__ float lane_bcast(float v, int srclane) {
    // srclane is wave-uniform (result of a full 64-lane reduction)
    return __uint_as_float((unsigned)__builtin_amdgcn_readlane((int)__float_as_uint(v), srclane));
}

__global__ void __launch_bounds__(NTHREADS, 2)
slater_logdet(const float* __restrict__ rs,     // [B,128,3]
              const float* __restrict__ kpts,   // [128,3]
              float* __restrict__ out)          // [B]
{
    __shared__ __align__(16) float A[NN * LDA];   // 67584 B
    __shared__ float kp[NN * 3];                  // 1536 B
    __shared__ int ipiv[NB];                      // pivot slot per panel step

    const int tid  = threadIdx.x;
    const int b    = blockIdx.x;
    const int lane = tid & 63;
    const int wave = tid >> 6;

    // ---- stage kpoints to LDS
    for (int idx = tid; idx < NN * 3; idx += NTHREADS)
        kp[idx] = kpts[idx];
    __syncthreads();

    // ---- generate slater matrix
    {
        const int i     = tid >> 1;          // row
        const int jbase = (tid & 1) << 6;    // 0 or 64
        const float r0 = rs[(b * NN + i) * 3 + 0];
        const float r1 = rs[(b * NN + i) * 3 + 1];
        const float r2 = rs[(b * NN + i) * 3 + 2];
        for (int jj = 0; jj < 64; jj += 4) {
            float v[4];
#pragma unroll
            for (int q = 0; q < 4; ++q) {
                const int j = jbase + jj + q;
                const float dot = r0 * kp[j * 3 + 0] + r1 * kp[j * 3 + 1] + r2 * kp[j * 3 + 2];
                // cos for j==0 and odd j; sin for even j>=2
                v[q] = ((j == 0) || (j & 1)) ? cosf(dot) : sinf(dot);
            }
            *(float4*)&A[i * LDA + jbase + jj] = make_float4(v[0], v[1], v[2], v[3]);
        }
    }

    float logsum = 0.0f;   // maintained uniformly across wave 0

    for (int kb = 0; kb < NN; kb += NB) {
        __syncthreads();   // A ready (generation or previous trailing GEMM)

        // ================= panel factorization: wave 0, in registers ==========
        if (wave == 0) {
            const int r0 = kb + lane;
            const int r1 = kb + 64 + lane;
            const bool h0 = (r0 < NN);
            const bool h1 = (r1 < NN);
            float x0[NB], x1[NB];
#pragma unroll
            for (int c = 0; c < NB; c += 4) {
                float4 t = h0 ? *(const float4*)&A[r0 * LDA + kb + c] : make_float4(0.f,0.f,0.f,0.f);
                x0[c] = t.x; x0[c+1] = t.y; x0[c+2] = t.z; x0[c+3] = t.w;
                float4 s = h1 ? *(const float4*)&A[r1 * LDA + kb + c] : make_float4(0.f,0.f,0.f,0.f);
                x1[c] = s.x; x1[c+1] = s.y; x1[c+2] = s.z; x1[c+3] = s.w;
            }
            int slot0 = h0 ? r0 : 999;   // current position under the pivot permutation
            int slot1 = h1 ? r1 : 999;

#pragma unroll
            for (int k = 0; k < NB; ++k) {
                const int gk = kb + k;
                // ---- pivot search over active rows (slot >= gk):
                // key = |val| bits (top 18) | slot (7b) | lane (6b) | which-half (1b)
                unsigned key = 0u;
                if (h0 && slot0 >= gk) {
                    key = (__float_as_uint(fabsf(x0[k])) & 0xFFFFC000u)
                        | ((unsigned)slot0 << 7) | ((unsigned)lane << 1);
                }
                if (h1 && slot1 >= gk) {
                    unsigned cand = (__float_as_uint(fabsf(x1[k])) & 0xFFFFC000u)
                                  | ((unsigned)slot1 << 7) | ((unsigned)lane << 1) | 1u;
                    if (cand > key) key = cand;
                }
#pragma unroll
                for (int off = 32; off > 0; off >>= 1) {
                    unsigned o = (unsigned)__shfl_xor((int)key, off, 64);
                    if (o > key) key = o;
                }
                const int psl   = (int)((key >> 7) & 127u);
                const int olane = (int)((key >> 1) & 63u);
                const int phi   = (int)(key & 1u);

                // ---- broadcast pivot row (cols k..NB-1) from its owner lane
                float u[NB];
#pragma unroll
                for (int c = k; c < NB; ++c) {
                    const float cand = phi ? x1[c] : x0[c];
                    u[c] = lane_bcast(cand, olane);
                }
                const float pivot = u[k];
                logsum += logf(fabsf(pivot));
                const float invp = 1.0f / pivot;

                if (lane == 0) ipiv[k] = psl;

                // ---- transposition (gk <-> psl) on slot bookkeeping
                if (slot0 == gk) slot0 = psl; else if (slot0 == psl) slot0 = gk;
                if (slot1 == gk) slot1 = psl; else if (slot1 == psl) slot1 = gk;

                // ---- scale + rank-1 update for still-active rows
                if (h0 && slot0 > gk) {
                    const float m = x0[k] * invp;
                    x0[k] = m;
#pragma unroll
                    for (int c = k + 1; c < NB; ++c) x0[c] = fmaf(-m, u[c], x0[c]);
                }
                if (h1 && slot1 > gk) {
                    const float m = x1[k] * invp;
                    x1[k] = m;
#pragma unroll
                    for (int c = k + 1; c < NB; ++c) x1[c] = fmaf(-m, u[c], x1[c]);
                }
            }
            // ---- scatter panel back to LDS in pivot order
            if (h0) {
#pragma unroll
                for (int c = 0; c < NB; c += 4)
                    *(float4*)&A[slot0 * LDA + kb + c] = make_float4(x0[c], x0[c+1], x0[c+2], x0[c+3]);
            }
            if (h1) {
#pragma unroll
                for (int c = 0; c < NB; c += 4)
                    *(float4*)&A[slot1 * LDA + kb + c] = make_float4(x1[c], x1[c+1], x1[c+2], x1[c+3]);
            }
        }
        __syncthreads();

        // ===== apply row swaps to non-panel columns; U12 forward-substitution ==
        if (tid < NN - NB) {
            const int col = (tid < kb) ? tid : tid + NB;
#pragma unroll
            for (int k = 0; k < NB; ++k) {
                const int psl = ipiv[k];
                const int gk  = kb + k;
                if (psl != gk) {
                    const float a0 = A[gk  * LDA + col];
                    const float a1 = A[psl * LDA + col];
                    A[gk  * LDA + col] = a1;
                    A[psl * LDA + col] = a0;
                }
            }
            if (col >= kb + NB) {   // U12 = L11^{-1} * A12, per-column in registers
                float c[NB];
#pragma unroll
                for (int m = 0; m < NB; ++m) c[m] = A[(kb + m) * LDA + col];
#pragma unroll
                for (int m = 1; m < NB; ++m) {
                    float acc = c[m];
#pragma unroll
                    for (int t = 0; t < m; ++t)
                        acc = fmaf(-A[(kb + m) * LDA + kb + t], c[t], acc);  // L11 broadcast reads
                    c[m] = acc;
                }
#pragma unroll
                for (int m = 0; m < NB; ++m) A[(kb + m) * LDA + col] = c[m];
            }
        }
        __syncthreads();

        // ================= trailing GEMM: A22 -= L21 * U12 =====================
        const int S = NN - kb - NB;
        if (S > 0) {
            const int nti = S >> 3;              // 8-row tiles
            const int ntj = S >> 2;              // 4-col tiles
            const int ntiles = nti * ntj;
            for (int tile = tid; tile < ntiles; tile += NTHREADS) {
                const int ti = tile / ntj;
                const int tj = tile - ti * ntj;
                const int i0 = kb + NB + (ti << 3);
                const int j0 = kb + NB + (tj << 2);
                float4 acc[8];
#pragma unroll
                for (int r = 0; r < 8; ++r) acc[r] = *(const float4*)&A[(i0 + r) * LDA + j0];
#pragma unroll
                for (int mc = 0; mc < 4; ++mc) {
                    float4 L[8];
#pragma unroll
                    for (int r = 0; r < 8; ++r)
                        L[r] = *(const float4*)&A[(i0 + r) * LDA + kb + (mc << 2)];
#pragma unroll
                    for (int mm = 0; mm < 4; ++mm) {
                        const float4 u4 = *(const float4*)&A[(kb + (mc << 2) + mm) * LDA + j0];
#pragma unroll
                        for (int r = 0; r < 8; ++r) {
                            const float lm = (mm == 0) ? L[r].x : (mm == 1) ? L[r].y
                                           : (mm == 2) ? L[r].z : L[r].w;
                            acc[r].x = fmaf(-lm, u4.x, acc[r].x);
                            acc[r].y = fmaf(-lm, u4.y, acc[r].y);
                            acc[r].z = fmaf(-lm, u4.z, acc[r].z);
                            acc[r].w = fmaf(-lm, u4.w, acc[r].w);
                        }
                    }
                }
#pragma unroll
                for (int r = 0; r < 8; ++r) *(float4*)&A[(i0 + r) * LDA + j0] = acc[r];
            }
        }
    }

    if (tid == 0) out[b] = logsum;
}

extern "C" void kernel_launch(void* const* d_in, const int* in_sizes, int n_in,
                              void* d_out, int out_size, void* d_ws, size_t ws_size,
                              hipStream_t stream) {
    const float* rs  = (const float*)d_in[0];
    const float* kpt = (const float*)d_in[1];
    float* o = (float*)d_out;
    const int B = in_sizes[0] / (NN * 3);
    hipLaunchKernelGGL(slater_logdet, dim3(B), dim3(NTHREADS), 0, stream, rs, kpt, o);
}

// Round 7
// 687.961 us; speedup vs baseline: 1.2544x; 1.2544x over previous
//
#include <hip/hip_runtime.h>
#include <math.h>

// LogSimpleSlater: A[b][i][j] = cos/sin(k_j . r_{b,i}); out[b] = log|det A_b|.
// One workgroup (256 threads) per walker, matrix in LDS (128x132 fp32).
// Blocked LU NB=16 with: DPP-based pivot argmax, ballot-compacted one-pass
// row permutation, lookahead (panel p+1 on wave0 || trailing GEMM on waves 1-3).
// NUMERICS: exact 1/p division + exact logf (approx rcp/log2 failed absmax).

#define NN 128
#define LDA 132      // row pitch in floats
#define NB 16
#define NTHREADS 256

__device__ __forceinline__ int imax2(int a, int b) { return a > b ? a : b; }

// max over each 16-lane DPP row; afterwards every lane holds its row's max
__device__ __forceinline__ int dpp_max16(int x) {
    int y;
    y = __builtin_amdgcn_update_dpp(0, x, 0xB1, 0xF, 0xF, true);  x = imax2(x, y); // quad_perm [1,0,3,2]
    y = __builtin_amdgcn_update_dpp(0, x, 0x4E, 0xF, 0xF, true);  x = imax2(x, y); // quad_perm [2,3,0,1]
    y = __builtin_amdgcn_update_dpp(0, x, 0x124, 0xF, 0xF, true); x = imax2(x, y); // row_ror:4
    y = __builtin_amdgcn_update_dpp(0, x, 0x128, 0xF, 0xF, true); x = imax2(x, y); // row_ror:8
    return x;
}

__device__ __forceinline__ float lane_bcastf(float v, int srclane) {
    return __uint_as_float((unsigned)__builtin_amdgcn_readlane((int)__float_as_uint(v), srclane));
}

// Panel factorization for cols [kb,kb+16), rows [kb,128). Wave 0 only.
// Produces L/U in-place (pivot-ordered), appends log|piv|, writes pair list.
__device__ __forceinline__ void panel_factor(float* __restrict__ A, const int kb,
                                             const int lane, float& logsum,
                                             int* __restrict__ pairs,
                                             int* __restrict__ paircnt) {
    const int r0 = kb + lane;
    const int r1 = kb + 64 + lane;
    const bool h0 = (r0 < NN);
    const bool h1 = (r1 < NN);
    float x0[NB], x1[NB];
#pragma unroll
    for (int c = 0; c < NB; c += 4) {
        float4 t = h0 ? *(const float4*)&A[r0 * LDA + kb + c] : make_float4(0.f, 0.f, 0.f, 0.f);
        x0[c] = t.x; x0[c + 1] = t.y; x0[c + 2] = t.z; x0[c + 3] = t.w;
        float4 s = h1 ? *(const float4*)&A[r1 * LDA + kb + c] : make_float4(0.f, 0.f, 0.f, 0.f);
        x1[c] = s.x; x1[c + 1] = s.y; x1[c + 2] = s.z; x1[c + 3] = s.w;
    }
    int slot0 = h0 ? r0 : 999;
    int slot1 = h1 ? r1 : 999;

#pragma unroll
    for (int k = 0; k < NB; ++k) {
        const int gk = kb + k;
        // key = |val| top-18 bits | slot(7) | lane(6) | half(1)
        int key = 0;
        if (h0 && slot0 >= gk)
            key = (int)((__float_as_uint(fabsf(x0[k])) & 0xFFFFC000u)
                        | ((unsigned)slot0 << 7) | ((unsigned)lane << 1));
        if (h1 && slot1 >= gk) {
            int c2 = (int)((__float_as_uint(fabsf(x1[k])) & 0xFFFFC000u)
                           | ((unsigned)slot1 << 7) | ((unsigned)lane << 1) | 1u);
            key = imax2(key, c2);
        }
        const int red = dpp_max16(key);
        const int kmax = imax2(imax2(__builtin_amdgcn_readlane(red, 0),
                                     __builtin_amdgcn_readlane(red, 16)),
                               imax2(__builtin_amdgcn_readlane(red, 32),
                                     __builtin_amdgcn_readlane(red, 48)));
        const int psl   = (kmax >> 7) & 127;
        const int olane = (kmax >> 1) & 63;
        const int phi   = kmax & 1;

        float u[NB];
#pragma unroll
        for (int c = k; c < NB; ++c)
            u[c] = lane_bcastf(phi ? x1[c] : x0[c], olane);
        const float pivot = u[k];
        logsum += logf(fabsf(pivot));          // exact log, exact div below
        const float invp = 1.0f / pivot;

        if (slot0 == gk) slot0 = psl; else if (slot0 == psl) slot0 = gk;
        if (slot1 == gk) slot1 = psl; else if (slot1 == psl) slot1 = gk;

        if (h0 && slot0 > gk) {
            const float m = x0[k] * invp;
            x0[k] = m;
#pragma unroll
            for (int c = k + 1; c < NB; ++c) x0[c] = fmaf(-m, u[c], x0[c]);
        }
        if (h1 && slot1 > gk) {
            const float m = x1[k] * invp;
            x1[k] = m;
#pragma unroll
            for (int c = k + 1; c < NB; ++c) x1[c] = fmaf(-m, u[c], x1[c]);
        }
    }

    // scatter panel back in pivot order
    if (h0) {
#pragma unroll
        for (int c = 0; c < NB; c += 4)
            *(float4*)&A[slot0 * LDA + kb + c] = make_float4(x0[c], x0[c+1], x0[c+2], x0[c+3]);
    }
    if (h1) {
#pragma unroll
        for (int c = 0; c < NB; c += 4)
            *(float4*)&A[slot1 * LDA + kb + c] = make_float4(x1[c], x1[c+1], x1[c+2], x1[c+3]);
    }

    // ballot-compacted (dst,src) pair list of moved rows (<= 32 pairs)
    const unsigned long long mv0 = __ballot(h0 && (slot0 != r0));
    const unsigned long long mv1 = __ballot(h1 && (slot1 != r1));
    const unsigned long long lt  = (1ull << lane) - 1ull;
    const int c0 = __popcll(mv0);
    if (h0 && slot0 != r0) pairs[__popcll(mv0 & lt)] = (slot0 << 8) | r0;
    if (h1 && slot1 != r1) pairs[c0 + __popcll(mv1 & lt)] = (slot1 << 8) | r1;
    if (lane == 0) *paircnt = c0 + __popcll(mv1);
}

// Apply row permutation (pair list) + U12 forward-substitution for one column.
__device__ __forceinline__ void perm_u12_col(float* __restrict__ A, const int kb,
                                             const int col,
                                             const int* __restrict__ pairs,
                                             const int m) {
    float v[32];
    int dst[32];
#pragma unroll
    for (int i = 0; i < 32; ++i) {
        if (i < m) {
            const int pr = pairs[i];
            dst[i] = pr >> 8;
            v[i] = A[(pr & 0xFF) * LDA + col];
        }
    }
#pragma unroll
    for (int i = 0; i < 32; ++i)
        if (i < m) A[dst[i] * LDA + col] = v[i];

    // U12 = L11^{-1} * col (rows kb..kb+15), unit-lower L11
    float c[NB];
#pragma unroll
    for (int mm = 0; mm < NB; ++mm) c[mm] = A[(kb + mm) * LDA + col];
#pragma unroll
    for (int mm = 1; mm < NB; ++mm) {
        float acc = c[mm];
#pragma unroll
        for (int t = 0; t < mm; ++t)
            acc = fmaf(-A[(kb + mm) * LDA + kb + t], c[t], acc);
        c[mm] = acc;
    }
#pragma unroll
    for (int mm = 0; mm < NB; ++mm) A[(kb + mm) * LDA + col] = c[mm];
}

// A22 -= L21 * U12 on rows [kb+16,128) x cols [col0, col0+ncols), 8x4 reg tiles.
__device__ __forceinline__ void gemm_tiles(float* __restrict__ A, const int kb,
                                           const int col0, const int ncols,
                                           const int idx0, const int nthr) {
    const int row0 = kb + NB;
    const int S = NN - row0;
    const int nti = S >> 3;
    const int ntj = ncols >> 2;
    const int ntiles = nti * ntj;
    for (int tile = idx0; tile < ntiles; tile += nthr) {
        const int ti = tile / ntj;
        const int tj = tile - ti * ntj;
        const int i0 = row0 + (ti << 3);
        const int j0 = col0 + (tj << 2);
        float4 acc[8];
#pragma unroll
        for (int r = 0; r < 8; ++r) acc[r] = *(const float4*)&A[(i0 + r) * LDA + j0];
#pragma unroll
        for (int mc = 0; mc < 4; ++mc) {
            float4 L[8];
#pragma unroll
            for (int r = 0; r < 8; ++r)
                L[r] = *(const float4*)&A[(i0 + r) * LDA + kb + (mc << 2)];
#pragma unroll
            for (int mm = 0; mm < 4; ++mm) {
                const float4 u4 = *(const float4*)&A[(kb + (mc << 2) + mm) * LDA + j0];
#pragma unroll
                for (int r = 0; r < 8; ++r) {
                    const float lm = (mm == 0) ? L[r].x : (mm == 1) ? L[r].y
                                   : (mm == 2) ? L[r].z : L[r].w;
                    acc[r].x = fmaf(-lm, u4.x, acc[r].x);
                    acc[r].y = fmaf(-lm, u4.y, acc[r].y);
                    acc[r].z = fmaf(-lm, u4.z, acc[r].z);
                    acc[r].w = fmaf(-lm, u4.w, acc[r].w);
                }
            }
        }
#pragma unroll
        for (int r = 0; r < 8; ++r) *(float4*)&A[(i0 + r) * LDA + j0] = acc[r];
    }
}

__global__ void __launch_bounds__(NTHREADS, 2)
slater_logdet(const float* __restrict__ rs,     // [B,128,3]
              const float* __restrict__ kpts,   // [128,3]
              float* __restrict__ out)          // [B]
{
    __shared__ __align__(16) float A[NN * LDA];   // 67584 B
    __shared__ float kp[NN * 3];
    __shared__ int pairs[32];
    __shared__ int paircnt;

    const int tid  = threadIdx.x;
    const int b    = blockIdx.x;
    const int lane = tid & 63;
    const int wave = tid >> 6;

    for (int idx = tid; idx < NN * 3; idx += NTHREADS) kp[idx] = kpts[idx];
    __syncthreads();

    // ---- generate slater matrix
    {
        const int i     = tid >> 1;
        const int jbase = (tid & 1) << 6;
        const float r0 = rs[(b * NN + i) * 3 + 0];
        const float r1 = rs[(b * NN + i) * 3 + 1];
        const float r2 = rs[(b * NN + i) * 3 + 2];
        for (int jj = 0; jj < 64; jj += 4) {
            float v[4];
#pragma unroll
            for (int q = 0; q < 4; ++q) {
                const int j = jbase + jj + q;
                const float dot = r0 * kp[j * 3 + 0] + r1 * kp[j * 3 + 1] + r2 * kp[j * 3 + 2];
                v[q] = ((j == 0) || (j & 1)) ? cosf(dot) : sinf(dot);
            }
            *(float4*)&A[i * LDA + jbase + jj] = make_float4(v[0], v[1], v[2], v[3]);
        }
    }
    __syncthreads();

    float logsum = 0.0f;
    if (wave == 0) panel_factor(A, 0, lane, logsum, pairs, &paircnt);
    __syncthreads();

    for (int p = 0; p < 7; ++p) {
        const int kb = p * NB;
        const int ncols_tr = NN - kb - NB;       // trailing cols beyond panel p

        // ---- phase A1: permute + forward-substitute ALL trailing cols
        const int m = paircnt;
        if (tid < ncols_tr) perm_u12_col(A, kb, kb + NB + tid, pairs, m);
        __syncthreads();

        // ---- phase A2: GEMM-update only the next panel's 16 columns
        gemm_tiles(A, kb, kb + NB, NB, tid, NTHREADS);
        __syncthreads();

        // ---- phase C: panel p+1 (wave 0) || trailing GEMM on remaining cols
        if (wave == 0) {
            panel_factor(A, kb + NB, lane, logsum, pairs, &paircnt);
        } else {
            gemm_tiles(A, kb, kb + 2 * NB, ncols_tr - NB, tid - 64, NTHREADS - 64);
        }
        __syncthreads();
    }

    if (tid == 0) out[b] = logsum;
}

extern "C" void kernel_launch(void* const* d_in, const int* in_sizes, int n_in,
                              void* d_out, int out_size, void* d_ws, size_t ws_size,
                              hipStream_t stream) {
    const float* rs  = (const float*)d_in[0];
    const float* kpt = (const float*)d_in[1];
    float* o = (float*)d_out;
    const int B = in_sizes[0] / (NN * 3);
    hipLaunchKernelGGL(slater_logdet, dim3(B), dim3(NTHREADS), 0, stream, rs, kpt, o);
}